// Round 5
// baseline (148.751 us; speedup 1.0000x reference)
//
#include <hip/hip_runtime.h>
#include <hip/hip_bf16.h>
#include <stdint.h>

typedef __attribute__((ext_vector_type(8))) __bf16 bf16x8;
typedef __attribute__((ext_vector_type(16))) float floatx16;

#if __has_builtin(__builtin_amdgcn_exp2f)
#define EXP2F(x) __builtin_amdgcn_exp2f(x)
#else
#define EXP2F(x) exp2f(x)
#endif

#define GAS __attribute__((address_space(1)))
#define LAS __attribute__((address_space(3)))

// sqrt(2*log2(e)): baked into normalized rows so dot = 2*log2(e)*cos and
// sim = exp2(dot) = exp(cos/0.5) with zero epilogue multiplies.
#define SCALE_SQRT 1.69864359f
#define JCH 16   // j-chunks per strip; grid = 64 x 16 = 1024 blocks (4/CU)
#define JPB 8    // j-tiles (64 cols) per block

// ---- sort pass 1: decode labels (int64 hedge), per-256-chunk hist + ranks ----
__global__ __launch_bounds__(256) void k_sort1(const int* __restrict__ raw,
                                               int* __restrict__ lab,
                                               int* __restrict__ ranks,
                                               int* __restrict__ cnt, int N) {
  __shared__ int h[64];
  __shared__ int s64;
  const int r = blockIdx.x * 256 + threadIdx.x;
  if (threadIdx.x < 64) {
    h[threadIdx.x] = 0;
    const int probe = raw[2 * threadIdx.x + 1];  // odd words all 0 => int64
    const unsigned long long b = __ballot(probe != 0);
    if (threadIdx.x == 0) s64 = (b == 0ull);
  }
  __syncthreads();
  const int l = (s64 ? raw[2 * r] : raw[r]) & 63;
  lab[r] = l;
  ranks[r] = atomicAdd(&h[l], 1);
  __syncthreads();
  if (threadIdx.x < 64) cnt[blockIdx.x * 64 + threadIdx.x] = h[threadIdx.x];
}

// ---- sort pass 2: scan chunk counts -> per-chunk bases + class cumsum -------
__global__ __launch_bounds__(256) void k_scan(const int* __restrict__ cnt,
                                              int* __restrict__ base,
                                              int* __restrict__ cum, int N) {
  __shared__ int tot[64];
  const int k = threadIdx.x;
  const int nch = N >> 8;  // 32
  if (k < 64) {
    int run = 0;
    for (int c = 0; c < nch; ++c) { base[c * 64 + k] = run; run += cnt[c * 64 + k]; }
    tot[k] = run;
  }
  __syncthreads();
  if (k == 0) {
    int run = 0;
    for (int i = 0; i < 64; ++i) { cum[i] = run; run += tot[i]; }
    cum[64] = run;
  }
  __syncthreads();
  for (int i = threadIdx.x; i < nch * 64; i += 256) base[i] += cum[i & 63];
}

// ---- prep: normalize + scale + bf16, scatter into label-sorted order --------
__global__ __launch_bounds__(256) void k_prep(const float* __restrict__ x,
                                              const int* __restrict__ lab,
                                              const int* __restrict__ ranks,
                                              const int* __restrict__ base,
                                              ushort* __restrict__ xb,
                                              int* __restrict__ labs, int N) {
  const int row = (blockIdx.x * 256 + threadIdx.x) >> 6;  // one wave per row
  const int lane = threadIdx.x & 63;
  if (row >= N) return;
  const int l = lab[row];
  const int slot = base[(row >> 8) * 64 + l] + ranks[row];
  const float2 v = ((const float2*)(x + (size_t)row * 128))[lane];
  float ss = v.x * v.x + v.y * v.y;
#pragma unroll
  for (int m = 1; m < 64; m <<= 1) ss += __shfl_xor(ss, m, 64);
  const float rn = SCALE_SQRT / fmaxf(sqrtf(ss), 1e-12f);
  __hip_bfloat162 o;
  o.x = __float2bfloat16(v.x * rn);
  o.y = __float2bfloat16(v.y * rn);
  ((__hip_bfloat162*)xb)[slot * 64 + lane] = o;
  if (lane == 0) labs[slot] = l;
}

// ---- main: full-matrix exp(x x^T/T) row sums, label-sorted ------------------
// Block 256 thr = 4 waves; wave w owns rows [i0+32w, i0+32w+32) x 64-col tiles.
// A fragments: direct global->reg (linear layout, L2-hot), loaded once.
// B: LDS 2x16 KB double-buffer, XOR-16 source-permuted swizzle, prefetch
// issued before compute, drained by the end-of-tile barrier. Small looped
// body (I-cache hot). Sorted labels => pos/diag epilogue is wave-uniform
// branch taken on ~1-2 of 8 tiles; plain tiles: exp2 + add only.
__global__ __launch_bounds__(256, 4) void k_sim(const ushort* __restrict__ xb,
                                                const int* __restrict__ labs,
                                                const int* __restrict__ cum,
                                                float* __restrict__ pneg,
                                                float* __restrict__ ppos, int N) {
  __shared__ ushort ldsB[2][64 * 128];   // 2 x 16 KB
  const int tid = threadIdx.x;
  const int lane = tid & 63;
  const int wv = tid >> 6;
  const int l31 = lane & 31, g2 = lane >> 5;
  const int l15 = lane & 15, g4 = lane >> 4;
  const int i0 = blockIdx.y * 128;
  const int c = blockIdx.x;
  const int jt0 = c * JPB;

  auto stageB = [&](int pbuf, int jrow0) {
#pragma unroll
    for (int it = 0; it < 4; ++it) {
      const int r0 = it * 16 + wv * 4;   // wave-uniform LDS row base
      const int lr = r0 + g4;
      const int kb = l15 ^ (lr & 15);    // XOR-16 source-permuted swizzle
      const ushort* gp = xb + (size_t)(jrow0 + lr) * 128 + kb * 8;
      __builtin_amdgcn_global_load_lds((GAS void*)gp, (LAS void*)&ldsB[pbuf][r0 * 128], 16, 0, 0);
    }
  };

  stageB(0, jt0 * 64);  // first B tile in flight immediately

  // A fragments global->reg: A[m=l31][k = kt*16 + g2*8 + (0..7)], linear xb
  bf16x8 afr[8];
  {
    const ushort* arow_p = xb + (size_t)(i0 + wv * 32 + l31) * 128 + g2 * 8;
#pragma unroll
    for (int kt = 0; kt < 8; ++kt)
      afr[kt] = *(const bf16x8*)(arow_p + kt * 16);
  }

  // wave-uniform positive column range (labels sorted => contiguous)
  const int wps = cum[labs[i0 + wv * 32]];
  const int wpe = cum[labs[i0 + wv * 32 + 31] + 1];

  // per-lane labels of the 16 rows this lane accumulates, packed 4x8b
  // C/D 32x32 layout: col = lane&31, row = (reg&3) + 8*(reg>>2) + 4*(lane>>5)
  int li_pack[4] = {0, 0, 0, 0};
#pragma unroll
  for (int t = 0; t < 16; ++t) {
    const int r = (t & 3) + 8 * (t >> 2) + 4 * g2;
    li_pack[t >> 2] |= labs[i0 + wv * 32 + r] << ((t & 3) * 8);
  }

  float neg[16], pos[16];
#pragma unroll
  for (int t = 0; t < 16; ++t) { neg[t] = 0.0f; pos[t] = 0.0f; }

  __syncthreads();  // B0 staged (per-wave vmcnt drained at barrier)

  auto tile = [&](int t, int buf) {
    const int j0 = (jt0 + t) * 64;
    if (t + 1 < JPB) stageB(buf ^ 1, j0 + 64);  // lands during compute

    floatx16 acc0 = (floatx16)(0.0f), acc1 = (floatx16)(0.0f);
#pragma unroll
    for (int kt = 0; kt < 8; ++kt) {
      const int kb = (kt * 2 + g2) ^ l15;  // (row&15)==l15 for both halves
      const bf16x8 b0 = *(const bf16x8*)&ldsB[buf][l31 * 128 + kb * 8];
      const bf16x8 b1 = *(const bf16x8*)&ldsB[buf][(32 + l31) * 128 + kb * 8];
      acc0 = __builtin_amdgcn_mfma_f32_32x32x16_bf16(afr[kt], b0, acc0, 0, 0, 0);
      acc1 = __builtin_amdgcn_mfma_f32_32x32x16_bf16(afr[kt], b1, acc1, 0, 0, 0);
    }

    const bool posT = (j0 < wpe) && (j0 + 64 > wps);  // wave-uniform
    if (!posT) {
#pragma unroll
      for (int reg = 0; reg < 16; ++reg)
        neg[reg] += EXP2F(acc0[reg]) + EXP2F(acc1[reg]);
    } else {
      const int lj0 = labs[j0 + l31];
      const int lj1 = labs[j0 + 32 + l31];
      const int dlt = j0 - (i0 + wv * 32);  // diag iff -64 < dlt < 32
      const bool dg = (dlt > -64) && (dlt < 32);
      auto epi = [&](bool DG) {
#pragma unroll
        for (int reg = 0; reg < 16; ++reg) {
          float e0 = EXP2F(acc0[reg]);
          float e1 = EXP2F(acc1[reg]);
          if (DG) {
            const int ir = (reg & 3) + 8 * (reg >> 2) + 4 * g2;
            if (ir == dlt + l31) e0 = 0.0f;        // self-similarity
            if (ir == dlt + 32 + l31) e1 = 0.0f;
          }
          const int liq = (li_pack[reg >> 2] >> ((reg & 3) * 8)) & 63;
          neg[reg] += e0 + e1;
          pos[reg] += (liq == lj0 ? e0 : 0.0f) + (liq == lj1 ? e1 : 0.0f);
        }
      };
      if (dg) epi(true); else epi(false);
    }
    __syncthreads();  // buf reads done; prefetch(t+1) drained here
  };

  for (int t = 0; t < JPB; t += 2) {  // small looped body, buffer parity only
    tile(t, 0);
    tile(t + 1, 1);
  }

  // ---- flush: wave owns its 32 rows; reduce over 32 cols, direct stores ----
#pragma unroll
  for (int t = 0; t < 16; ++t) {
    float n = neg[t], p = pos[t];
#pragma unroll
    for (int m = 1; m < 32; m <<= 1) {  // stays within each 32-lane half
      n += __shfl_xor(n, m, 64);
      p += __shfl_xor(p, m, 64);
    }
    if (l31 == 0) {
      const int r = i0 + wv * 32 + (t & 3) + 8 * (t >> 2) + 4 * g2;
      pneg[(size_t)c * N + r] = n;
      ppos[(size_t)c * N + r] = p;
    }
  }
}

// ---- finalize: sum partials + mean(log(neg*cnt/pos)) ------------------------
__global__ __launch_bounds__(1024) void k_final(const float* __restrict__ pneg,
                                                const float* __restrict__ ppos,
                                                const int* __restrict__ labs,
                                                const int* __restrict__ cum,
                                                float* __restrict__ out, int N) {
  double s = 0.0;
  for (int i = threadIdx.x; i < N; i += 1024) {
    float n = 0.0f, p = 0.0f;
#pragma unroll
    for (int c = 0; c < JCH; ++c) {
      n += pneg[(size_t)c * N + i];
      p += ppos[(size_t)c * N + i];
    }
    const int l = labs[i];
    const float cnt = (float)(cum[l + 1] - cum[l] - 1);
    s += (double)logf(n * cnt / p);
  }
#pragma unroll
  for (int m = 1; m < 64; m <<= 1) s += __shfl_xor(s, m, 64);
  __shared__ double wsum[16];
  if ((threadIdx.x & 63) == 0) wsum[threadIdx.x >> 6] = s;
  __syncthreads();
  if (threadIdx.x == 0) {
    double tot = 0.0;
    for (int w = 0; w < 16; ++w) tot += wsum[w];
    out[0] = (float)(tot / (double)N);
  }
}

extern "C" void kernel_launch(void* const* d_in, const int* in_sizes, int n_in,
                              void* d_out, int out_size, void* d_ws, size_t ws_size,
                              hipStream_t stream) {
  const float* x = (const float*)d_in[0];
  const int* raw_label = (const int*)d_in[1];
  const int N = in_sizes[1];  // 8192
  char* ws = (char*)d_ws;
  ushort* xb = (ushort*)ws;                          // N*128 bf16 = 2 MB
  float* pneg = (float*)(ws + (size_t)N * 128 * 2);  // JCH*N f32
  float* ppos = pneg + (size_t)JCH * N;              // JCH*N f32
  int* lab = (int*)(ppos + (size_t)JCH * N);         // N
  int* ranks = lab + N;                              // N
  int* labs = ranks + N;                             // N (sorted labels)
  int* cnt = labs + N;                               // (N/256)*64
  int* base = cnt + (N >> 8) * 64;                   // (N/256)*64
  int* cum = base + (N >> 8) * 64;                   // 65
  float* out = (float*)d_out;

  k_sort1<<<dim3(N / 256), dim3(256), 0, stream>>>(raw_label, lab, ranks, cnt, N);
  k_scan<<<dim3(1), dim3(256), 0, stream>>>(cnt, base, cum, N);
  k_prep<<<dim3(N / 4), dim3(256), 0, stream>>>(x, lab, ranks, base, xb, labs, N);
  k_sim<<<dim3(JCH, N / 128), dim3(256), 0, stream>>>(xb, labs, cum, pneg, ppos, N);
  k_final<<<dim3(1), dim3(1024), 0, stream>>>(pneg, ppos, labs, cum, out, N);
}

// Round 6
// 114.707 us; speedup vs baseline: 1.2968x; 1.2968x over previous
//
#include <hip/hip_runtime.h>
#include <hip/hip_bf16.h>
#include <stdint.h>

typedef __attribute__((ext_vector_type(8))) __bf16 bf16x8;
typedef __attribute__((ext_vector_type(16))) float floatx16;

#if __has_builtin(__builtin_amdgcn_exp2f)
#define EXP2F(x) __builtin_amdgcn_exp2f(x)
#else
#define EXP2F(x) exp2f(x)
#endif

#define GAS __attribute__((address_space(1)))
#define LAS __attribute__((address_space(3)))

// sqrt(2*log2(e)): baked into normalized rows so dot = 2*log2(e)*cos and
// sim = exp2(dot) = exp(cos/0.5) with zero epilogue multiplies.
#define SCALE_SQRT 1.69864359f
#define JCH 16   // j-chunks per strip; grid = 64 x 16 = 1024 blocks
#define JPB 8    // j-tiles (64 cols) per block

// ---- sort pass 1: decode labels (int64 hedge), per-256-chunk hist + ranks ----
__global__ __launch_bounds__(256) void k_sort1(const int* __restrict__ raw,
                                               int* __restrict__ lab,
                                               int* __restrict__ ranks,
                                               int* __restrict__ cnt, int N) {
  __shared__ int h[64];
  __shared__ int s64;
  const int r = blockIdx.x * 256 + threadIdx.x;
  if (threadIdx.x < 64) {
    h[threadIdx.x] = 0;
    const int probe = raw[2 * threadIdx.x + 1];  // odd words all 0 => int64
    const unsigned long long b = __ballot(probe != 0);
    if (threadIdx.x == 0) s64 = (b == 0ull);
  }
  __syncthreads();
  const int l = (s64 ? raw[2 * r] : raw[r]) & 63;
  lab[r] = l;
  ranks[r] = atomicAdd(&h[l], 1);
  __syncthreads();
  if (threadIdx.x < 64) cnt[blockIdx.x * 64 + threadIdx.x] = h[threadIdx.x];
}

// ---- sort pass 2: scan chunk counts -> per-chunk bases + class cumsum -------
__global__ __launch_bounds__(256) void k_scan(const int* __restrict__ cnt,
                                              int* __restrict__ base,
                                              int* __restrict__ cum, int N) {
  __shared__ int tot[64];
  const int k = threadIdx.x;
  const int nch = N >> 8;  // 32
  if (k < 64) {
    int run = 0;
    for (int c = 0; c < nch; ++c) { base[c * 64 + k] = run; run += cnt[c * 64 + k]; }
    tot[k] = run;
  }
  __syncthreads();
  if (k == 0) {
    int run = 0;
    for (int i = 0; i < 64; ++i) { cum[i] = run; run += tot[i]; }
    cum[64] = run;
  }
  __syncthreads();
  for (int i = threadIdx.x; i < nch * 64; i += 256) base[i] += cum[i & 63];
}

// ---- prep: normalize + scale + bf16, scatter into label-sorted order --------
__global__ __launch_bounds__(256) void k_prep(const float* __restrict__ x,
                                              const int* __restrict__ lab,
                                              const int* __restrict__ ranks,
                                              const int* __restrict__ base,
                                              ushort* __restrict__ xb,
                                              int* __restrict__ labs, int N) {
  const int row = (blockIdx.x * 256 + threadIdx.x) >> 6;  // one wave per row
  const int lane = threadIdx.x & 63;
  if (row >= N) return;
  const int l = lab[row];
  const int slot = base[(row >> 8) * 64 + l] + ranks[row];
  const float2 v = ((const float2*)(x + (size_t)row * 128))[lane];
  float ss = v.x * v.x + v.y * v.y;
#pragma unroll
  for (int m = 1; m < 64; m <<= 1) ss += __shfl_xor(ss, m, 64);
  const float rn = SCALE_SQRT / fmaxf(sqrtf(ss), 1e-12f);
  __hip_bfloat162 o;
  o.x = __float2bfloat16(v.x * rn);
  o.y = __float2bfloat16(v.y * rn);
  ((__hip_bfloat162*)xb)[slot * 64 + lane] = o;
  if (lane == 0) labs[slot] = l;
}

// ---- main: full-matrix exp(x x^T/T) row sums, label-sorted ------------------
// Block 256 thr = 4 waves; wave w owns rows [i0+32w, +32) x 64-col j-tiles.
// A fragments: direct global->reg (L2-hot), loaded once (32 VGPRs).
// B: LDS 2x16 KB double-buffer, XOR-16 source-permuted swizzle; prefetch
// issued before compute, drained by the end-of-tile barrier.
// __launch_bounds__(256,3): ~170-reg cap -> NO spills (R5's killer), 3
// blocks/CU co-tenancy masks barrier drains. Sorted labels => pos/diag
// epilogue on ~1-2 of 8 tiles; plain tiles: exp2 + add only.
__global__ __launch_bounds__(256, 3) void k_sim(const ushort* __restrict__ xb,
                                                const int* __restrict__ labs,
                                                const int* __restrict__ cum,
                                                float* __restrict__ pneg,
                                                float* __restrict__ ppos, int N) {
  __shared__ ushort ldsB[2][64 * 128];   // 2 x 16 KB
  const int tid = threadIdx.x;
  const int lane = tid & 63;
  const int wv = tid >> 6;
  const int l31 = lane & 31, g2 = lane >> 5;
  const int l15 = lane & 15, g4 = lane >> 4;
  const int i0 = blockIdx.y * 128;
  const int c = blockIdx.x;
  const int jt0 = c * JPB;

  // ---- first B tile staging (XOR-16 source-permuted swizzle) ----
  {
    const int jrow0 = jt0 * 64;
#pragma unroll
    for (int it = 0; it < 4; ++it) {
      const int r0 = it * 16 + wv * 4;   // wave-uniform LDS row base
      const int lr = r0 + g4;
      const int kb = l15 ^ (lr & 15);
      const ushort* gp = xb + (size_t)(jrow0 + lr) * 128 + kb * 8;
      __builtin_amdgcn_global_load_lds((GAS void*)gp, (LAS void*)&ldsB[0][r0 * 128], 16, 0, 0);
    }
  }

  // A fragments global->reg: A[m=l31][k = kt*16 + g2*8 + (0..7)], linear xb
  bf16x8 afr[8];
  {
    const ushort* arow_p = xb + (size_t)(i0 + wv * 32 + l31) * 128 + g2 * 8;
#pragma unroll
    for (int kt = 0; kt < 8; ++kt)
      afr[kt] = *(const bf16x8*)(arow_p + kt * 16);
  }

  // wave-uniform positive column range (labels sorted => contiguous)
  const int wps = cum[labs[i0 + wv * 32]];
  const int wpe = cum[labs[i0 + wv * 32 + 31] + 1];

  // per-lane labels of the 16 rows this lane accumulates, packed 4x8b
  // C/D 32x32 layout: col = lane&31, row = (reg&3) + 8*(reg>>2) + 4*(lane>>5)
  int li_pack[4] = {0, 0, 0, 0};
#pragma unroll
  for (int t = 0; t < 16; ++t) {
    const int r = (t & 3) + 8 * (t >> 2) + 4 * g2;
    li_pack[t >> 2] |= labs[i0 + wv * 32 + r] << ((t & 3) * 8);
  }

  // B LDS element offsets for row l31 (row 32+l31 is +64*128 elements, folds
  // into the ds_read immediate offset)
  int baddr[8];
#pragma unroll
  for (int kt = 0; kt < 8; ++kt)
    baddr[kt] = l31 * 128 + (((kt * 2 + g2) ^ l15) * 8);

  float neg[16], pos[16];
#pragma unroll
  for (int t = 0; t < 16; ++t) { neg[t] = 0.0f; pos[t] = 0.0f; }

  __syncthreads();  // B0 staged (per-wave vmcnt drained at barrier)

  for (int t = 0; t < JPB; ++t) {
    const int j0 = (jt0 + t) * 64;
    const ushort* bbase = (t & 1) ? ldsB[1] : ldsB[0];
    ushort* bnext = (t & 1) ? ldsB[0] : ldsB[1];
    if (t + 1 < JPB) {  // prefetch next B; lands during this tile's compute
#pragma unroll
      for (int it = 0; it < 4; ++it) {
        const int r0 = it * 16 + wv * 4;
        const int lr = r0 + g4;
        const int kb = l15 ^ (lr & 15);
        const ushort* gp = xb + (size_t)(j0 + 64 + lr) * 128 + kb * 8;
        __builtin_amdgcn_global_load_lds((GAS void*)gp, (LAS void*)&bnext[r0 * 128], 16, 0, 0);
      }
    }

    floatx16 acc0 = (floatx16)(0.0f), acc1 = (floatx16)(0.0f);
#pragma unroll
    for (int kt = 0; kt < 8; ++kt) {
      const bf16x8 b0 = *(const bf16x8*)&bbase[baddr[kt]];
      const bf16x8 b1 = *(const bf16x8*)&bbase[baddr[kt] + 32 * 128];  // imm offset
      acc0 = __builtin_amdgcn_mfma_f32_32x32x16_bf16(afr[kt], b0, acc0, 0, 0, 0);
      acc1 = __builtin_amdgcn_mfma_f32_32x32x16_bf16(afr[kt], b1, acc1, 0, 0, 0);
    }

    const bool posT = (j0 < wpe) && (j0 + 64 > wps);  // wave-uniform
    if (!posT) {
#pragma unroll
      for (int reg = 0; reg < 16; ++reg)
        neg[reg] += EXP2F(acc0[reg]) + EXP2F(acc1[reg]);
    } else {
      const int lj0 = labs[j0 + l31];
      const int lj1 = labs[j0 + 32 + l31];
      const int dlt = j0 - (i0 + wv * 32);  // diag iff -64 < dlt < 32
      const bool dg = (dlt > -64) && (dlt < 32);
#pragma unroll
      for (int reg = 0; reg < 16; ++reg) {
        float e0 = EXP2F(acc0[reg]);
        float e1 = EXP2F(acc1[reg]);
        if (dg) {
          const int ir = (reg & 3) + 8 * (reg >> 2) + 4 * g2;
          if (ir == dlt + l31) e0 = 0.0f;        // self-similarity
          if (ir == dlt + 32 + l31) e1 = 0.0f;
        }
        const int liq = (li_pack[reg >> 2] >> ((reg & 3) * 8)) & 63;
        neg[reg] += e0 + e1;
        pos[reg] += (liq == lj0 ? e0 : 0.0f) + (liq == lj1 ? e1 : 0.0f);
      }
    }
    __syncthreads();  // bbase reads done; prefetch(t+1) drained here
  }

  // ---- flush: wave owns its 32 rows; reduce over 32 cols, direct stores ----
#pragma unroll
  for (int t = 0; t < 16; ++t) {
    float n = neg[t], p = pos[t];
#pragma unroll
    for (int m = 1; m < 32; m <<= 1) {  // stays within each 32-lane half
      n += __shfl_xor(n, m, 64);
      p += __shfl_xor(p, m, 64);
    }
    if (l31 == 0) {
      const int r = i0 + wv * 32 + (t & 3) + 8 * (t >> 2) + 4 * g2;
      pneg[(size_t)c * N + r] = n;
      ppos[(size_t)c * N + r] = p;
    }
  }
}

// ---- finalize: sum partials + mean(log(neg*cnt/pos)) ------------------------
__global__ __launch_bounds__(1024) void k_final(const float* __restrict__ pneg,
                                                const float* __restrict__ ppos,
                                                const int* __restrict__ labs,
                                                const int* __restrict__ cum,
                                                float* __restrict__ out, int N) {
  double s = 0.0;
  for (int i = threadIdx.x; i < N; i += 1024) {
    float n = 0.0f, p = 0.0f;
#pragma unroll
    for (int c = 0; c < JCH; ++c) {
      n += pneg[(size_t)c * N + i];
      p += ppos[(size_t)c * N + i];
    }
    const int l = labs[i];
    const float cnt = (float)(cum[l + 1] - cum[l] - 1);
    s += (double)logf(n * cnt / p);
  }
#pragma unroll
  for (int m = 1; m < 64; m <<= 1) s += __shfl_xor(s, m, 64);
  __shared__ double wsum[16];
  if ((threadIdx.x & 63) == 0) wsum[threadIdx.x >> 6] = s;
  __syncthreads();
  if (threadIdx.x == 0) {
    double tot = 0.0;
    for (int w = 0; w < 16; ++w) tot += wsum[w];
    out[0] = (float)(tot / (double)N);
  }
}

extern "C" void kernel_launch(void* const* d_in, const int* in_sizes, int n_in,
                              void* d_out, int out_size, void* d_ws, size_t ws_size,
                              hipStream_t stream) {
  const float* x = (const float*)d_in[0];
  const int* raw_label = (const int*)d_in[1];
  const int N = in_sizes[1];  // 8192
  char* ws = (char*)d_ws;
  ushort* xb = (ushort*)ws;                          // N*128 bf16 = 2 MB
  float* pneg = (float*)(ws + (size_t)N * 128 * 2);  // JCH*N f32
  float* ppos = pneg + (size_t)JCH * N;              // JCH*N f32
  int* lab = (int*)(ppos + (size_t)JCH * N);         // N
  int* ranks = lab + N;                              // N
  int* labs = ranks + N;                             // N (sorted labels)
  int* cnt = labs + N;                               // (N/256)*64
  int* base = cnt + (N >> 8) * 64;                   // (N/256)*64
  int* cum = base + (N >> 8) * 64;                   // 65
  float* out = (float*)d_out;

  k_sort1<<<dim3(N / 256), dim3(256), 0, stream>>>(raw_label, lab, ranks, cnt, N);
  k_scan<<<dim3(1), dim3(256), 0, stream>>>(cnt, base, cum, N);
  k_prep<<<dim3(N / 4), dim3(256), 0, stream>>>(x, lab, ranks, base, xb, labs, N);
  k_sim<<<dim3(JCH, N / 128), dim3(256), 0, stream>>>(xb, labs, cum, pneg, ppos, N);
  k_final<<<dim3(1), dim3(1024), 0, stream>>>(pneg, ppos, labs, cum, out, N);
}